// Round 14
// baseline (255.426 us; speedup 1.0000x reference)
//
#include <hip/hip_runtime.h>

// out[n][o] = sum_{s,i} tanh(slope[s][i][o]*x[n][i] - thres[s][i][o]) * ampli[s][i][o]^2
// N_DATA=128, N_SYN=8, IN_DIM=784, OUT_DIM=128
//
// R3:  occupancy 16% -> i-split 4x (1792 blocks).
// R8:  atomic-fanin theory -> R12 refuted (dur flat).
// R12/R13: two-phase; phase2 rebuilt (float4 gather) -> only -4.6us.
//      Inference: phase1 ~30us (2-3x pipe floor) but NEVER directly measured
//      (fills at ~46us flood top-5).
// R14: MEASUREMENT PROBE. phase1 body repeated 4x inside one dispatch
//      (REPEAT=4). __restrict__ dropped on phase1 so ws-stores may alias
//      params -> compiler must re-load/re-compute every rep (no CSE).
//      Stores are idempotent -> results identical. The probe dispatch
//      (~4x phase1) rises above the fills -> real counters for phase1.
//      Decision tree pre-committed in journal: visible->read regime
//      (VALUBusy/HBM); invisible->phase1 at floor, overhead dominates.

#define N_DATA  128
#define N_SYN   8
#define IN_DIM  784
#define OUT_DIM 128

#define NTILE   32    // n per block (phase 1)
#define NACC    16    // n per thread
#define ICHUNK  14    // i per block
#define NICHUNK 56    // 784 / 14
#define NTILES  4     // 128 / 32
#define NBLK1   (NTILES * N_SYN * NICHUNK)   // 1792
#define FANIN   (N_SYN * NICHUNK)            // 448 partial tiles per ntile
#define REPEAT  4     // probe multiplier for phase1 compute

__global__ __launch_bounds__(256)
void psl_phase1_probe(const float* x,      // [128][784]      (no __restrict__!)
                      const float* thres,  // [8][784][128]
                      const float* slope,  // [8][784][128]
                      const float* ampli,  // [8][784][128]
                      float* ws)           // [1792][32][128] partials
{
    const int t    = threadIdx.x;
    const int o    = t & 127;       // lane->o, coalesced param loads
    const int nsub = t >> 7;        // 0/1, wave-uniform

    int bid = blockIdx.x;
    const int ic    = bid % NICHUNK; bid /= NICHUNK;
    const int s     = bid % N_SYN;   bid /= N_SYN;
    const int ntile = bid;           // 0..3

    const int i0 = ic * ICHUNK;

    // x tile staged in LDS: [i][n], 14*32*4 = 1792 B (once; reused all reps)
    __shared__ float xs[ICHUNK][NTILE];
    for (int idx = t; idx < ICHUNK * NTILE; idx += 256) {
        const int nl = idx & (NTILE - 1);
        const int il = idx >> 5;
        xs[il][nl] = x[(ntile * NTILE + nl) * IN_DIM + i0 + il];
    }
    __syncthreads();

    const float C = 2.8853900817779268f;  // 2*log2(e)
    const int pbase = (s * IN_DIM + i0) * OUT_DIM + o;
    float* wsb = ws + (size_t)blockIdx.x * (NTILE * OUT_DIM);

#pragma unroll 1
    for (int rep = 0; rep < REPEAT; ++rep) {
        float acc[NACC];
#pragma unroll
        for (int k = 0; k < NACC; ++k) acc[k] = 0.f;
        float suma2 = 0.f;

#pragma unroll
        for (int il = 0; il < ICHUNK; ++il) {
            const int pidx = pbase + il * OUT_DIM;
            const float sl = slope[pidx];
            const float th = thres[pidx];
            const float am = ampli[pidx];

            const float a2   = am * am;
            suma2 += a2;                       // n-independent term, hoisted
            const float m2a2 = -2.f * a2;
            const float slC  = sl * C;
            const float thC  = th * C;

            // broadcast float4 reads (same address all lanes -> conflict-free)
            const float4* xrow = reinterpret_cast<const float4*>(&xs[il][nsub * NACC]);
#pragma unroll
            for (int q = 0; q < 4; ++q) {
                const float4 xv = xrow[q];
                {
                    float z = __builtin_fmaf(slC, xv.x, -thC);
                    float r = __builtin_amdgcn_rcpf(__builtin_amdgcn_exp2f(z) + 1.f);
                    acc[4*q+0] = __builtin_fmaf(m2a2, r, acc[4*q+0]);
                }
                {
                    float z = __builtin_fmaf(slC, xv.y, -thC);
                    float r = __builtin_amdgcn_rcpf(__builtin_amdgcn_exp2f(z) + 1.f);
                    acc[4*q+1] = __builtin_fmaf(m2a2, r, acc[4*q+1]);
                }
                {
                    float z = __builtin_fmaf(slC, xv.z, -thC);
                    float r = __builtin_amdgcn_rcpf(__builtin_amdgcn_exp2f(z) + 1.f);
                    acc[4*q+2] = __builtin_fmaf(m2a2, r, acc[4*q+2]);
                }
                {
                    float z = __builtin_fmaf(slC, xv.w, -thC);
                    float r = __builtin_amdgcn_rcpf(__builtin_amdgcn_exp2f(z) + 1.f);
                    acc[4*q+3] = __builtin_fmaf(m2a2, r, acc[4*q+3]);
                }
            }
        }

        // idempotent store: same values every rep, coalesced across o
#pragma unroll
        for (int k = 0; k < NACC; ++k) {
            wsb[(nsub * NACC + k) * OUT_DIM + o] = acc[k] + suma2;
        }
    }
}

// one block per n, 1024 threads: 32 j-groups x 32 float4-columns (R13, kept)
__global__ __launch_bounds__(1024)
void psl_phase2(const float* __restrict__ ws,   // [1792][32][128]
                float* __restrict__ out)        // [128][128]
{
    const int t  = threadIdx.x;      // 0..1023
    const int g  = t >> 5;           // 0..31 : j-group
    const int o4 = t & 31;           // float4 column (o = o4*4..o4*4+3)
    const int n  = blockIdx.x;       // 0..127
    const int ntile = n >> 5;
    const int nl    = n & 31;

    __shared__ float red[32][OUT_DIM];   // 16 KB

    const float4* base = reinterpret_cast<const float4*>(
        ws + (((size_t)ntile * FANIN * NTILE + nl) * OUT_DIM)) + o4;
    const size_t jstep = (size_t)NTILE * OUT_DIM / 4;   // 1024 float4 per j

    float4 acc = make_float4(0.f, 0.f, 0.f, 0.f);
#pragma unroll
    for (int m = 0; m < FANIN / 32; ++m) {              // 14 iterations
        const float4 v = base[(size_t)(g + 32 * m) * jstep];
        acc.x += v.x; acc.y += v.y; acc.z += v.z; acc.w += v.w;
    }
    *reinterpret_cast<float4*>(&red[g][o4 * 4]) = acc;
    __syncthreads();

    if (t < OUT_DIM) {
        float s = 0.f;
#pragma unroll
        for (int g2 = 0; g2 < 32; ++g2) s += red[g2][t];
        out[n * OUT_DIM + t] = s;
    }
}

extern "C" void kernel_launch(void* const* d_in, const int* in_sizes, int n_in,
                              void* d_out, int out_size, void* d_ws, size_t ws_size,
                              hipStream_t stream) {
    const float* x     = (const float*)d_in[0];
    const float* thres = (const float*)d_in[1];
    const float* slope = (const float*)d_in[2];
    const float* ampli = (const float*)d_in[3];
    float* out = (float*)d_out;
    float* ws  = (float*)d_ws;   // uses 1792*32*128*4 = 29.36 MB

    psl_phase1_probe<<<NBLK1, 256, 0, stream>>>(x, thres, slope, ampli, ws);
    psl_phase2<<<N_DATA, 1024, 0, stream>>>(ws, out);
}

// Round 17
// 103.066 us; speedup vs baseline: 2.4783x; 2.4783x over previous
//
#include <hip/hip_runtime.h>

// out[n][o] = sum_{s,i} tanh(slope[s][i][o]*x[n][i] - thres[s][i][o]) * ampli[s][i][o]^2
// N_DATA=128, N_SYN=8, IN_DIM=784, OUT_DIM=128
//
// R3:  occupancy 16% -> i-split 4x (1792 blocks).
// R8/R12: atomics are NOT the bottleneck (two-phase was flat).
// R13: phase2 float4 gather -> -4.6us; phase1 ~30us inferred.
// R14: probe: VGPR=152 (full-unroll hoists 42 param loads), VALUBusy 41%,
//      HBM 2%, occupancy ~11% -> phase1 is LATENCY-bound from VGPR-crippled
//      occupancy (3 waves/SIMD vs 7 available). VALU-busy/rep ~20us = the
//      real issue floor.
// R15: single kernel again (atomics, phase2+gap removed). il-loop rebuilt as
//      2-deep ROLLING REGISTER PREFETCH with #pragma unroll 1 (9 loads in
//      flight, ~60 VGPR) + __launch_bounds__(256,6) cap -> 6+ waves/SIMD.
//      Target: stall fraction 60% -> ~20%, phase1 ~30 -> ~18-20us.

#define N_DATA  128
#define N_SYN   8
#define IN_DIM  784
#define OUT_DIM 128

#define NTILE   32    // n per block
#define NACC    16    // n per thread (2 nsub halves)
#define ICHUNK  14    // i per block
#define NICHUNK 56    // 784 / 14
#define NTILES  4     // 128 / 32
#define NBLK    (NTILES * N_SYN * NICHUNK)   // 1792

__global__ __launch_bounds__(256, 6)   // cap VGPR ~85 -> >=6 waves/SIMD
void psl_fused(const float* __restrict__ x,      // [128][784]
               const float* __restrict__ thres,  // [8][784][128]
               const float* __restrict__ slope,  // [8][784][128]
               const float* __restrict__ ampli,  // [8][784][128]
               float* __restrict__ out)          // [128][128]
{
    const int t    = threadIdx.x;
    const int o    = t & 127;       // lane->o, coalesced param loads
    const int nsub = t >> 7;        // 0/1, wave-uniform

    int bid = blockIdx.x;
    const int ic    = bid % NICHUNK; bid /= NICHUNK;
    const int s     = bid % N_SYN;   bid /= N_SYN;
    const int ntile = bid;           // 0..3

    const int i0    = ic * ICHUNK;
    const int nbase = ntile * NTILE + nsub * NACC;

    // x tile staged in LDS: [i][n], 14*32*4 = 1792 B
    __shared__ float xs[ICHUNK][NTILE];
    for (int idx = t; idx < ICHUNK * NTILE; idx += 256) {
        const int nl = idx & (NTILE - 1);
        const int il = idx >> 5;
        xs[il][nl] = x[(ntile * NTILE + nl) * IN_DIM + i0 + il];
    }
    __syncthreads();

    float acc[NACC];
#pragma unroll
    for (int k = 0; k < NACC; ++k) acc[k] = 0.f;
    float suma2 = 0.f;

    const float C = 2.8853900817779268f;  // 2*log2(e)
    const int pbase = (s * IN_DIM + i0) * OUT_DIM + o;

    // 2-deep rolling prefetch: il consumes P[il] while P[il+2] is in flight.
    float sl0 = slope[pbase];
    float th0 = thres[pbase];
    float am0 = ampli[pbase];
    float sl1 = slope[pbase + OUT_DIM];
    float th1 = thres[pbase + OUT_DIM];
    float am1 = ampli[pbase + OUT_DIM];

#pragma unroll 1
    for (int il = 0; il < ICHUNK; ++il) {
        float sl2 = 0.f, th2 = 0.f, am2 = 0.f;
        if (il + 2 < ICHUNK) {               // uniform scalar branch
            const int pidx = pbase + (il + 2) * OUT_DIM;
            sl2 = slope[pidx];
            th2 = thres[pidx];
            am2 = ampli[pidx];
        }

        const float a2   = am0 * am0;
        suma2 += a2;                          // n-independent term, hoisted
        const float m2a2 = -2.f * a2;
        const float slC  = sl0 * C;
        const float thC  = th0 * C;

        // broadcast float4 reads (same address across all lanes -> conflict-free)
        const float4* xrow = reinterpret_cast<const float4*>(&xs[il][nsub * NACC]);
#pragma unroll
        for (int q = 0; q < 4; ++q) {
            const float4 xv = xrow[q];
            {
                float z = __builtin_fmaf(slC, xv.x, -thC);
                float r = __builtin_amdgcn_rcpf(__builtin_amdgcn_exp2f(z) + 1.f);
                acc[4*q+0] = __builtin_fmaf(m2a2, r, acc[4*q+0]);
            }
            {
                float z = __builtin_fmaf(slC, xv.y, -thC);
                float r = __builtin_amdgcn_rcpf(__builtin_amdgcn_exp2f(z) + 1.f);
                acc[4*q+1] = __builtin_fmaf(m2a2, r, acc[4*q+1]);
            }
            {
                float z = __builtin_fmaf(slC, xv.z, -thC);
                float r = __builtin_amdgcn_rcpf(__builtin_amdgcn_exp2f(z) + 1.f);
                acc[4*q+2] = __builtin_fmaf(m2a2, r, acc[4*q+2]);
            }
            {
                float z = __builtin_fmaf(slC, xv.w, -thC);
                float r = __builtin_amdgcn_rcpf(__builtin_amdgcn_exp2f(z) + 1.f);
                acc[4*q+3] = __builtin_fmaf(m2a2, r, acc[4*q+3]);
            }
        }

        // rotate the pipeline
        sl0 = sl1; th0 = th1; am0 = am1;
        sl1 = sl2; th1 = th2; am1 = am2;
    }

    // tanh*a2 = a2 - 2*a2*r ; the "+a2 per i" part is suma2, added once here
#pragma unroll
    for (int k = 0; k < NACC; ++k) {
        atomicAdd(&out[(nbase + k) * OUT_DIM + o], acc[k] + suma2);
    }
}

extern "C" void kernel_launch(void* const* d_in, const int* in_sizes, int n_in,
                              void* d_out, int out_size, void* d_ws, size_t ws_size,
                              hipStream_t stream) {
    const float* x     = (const float*)d_in[0];
    const float* thres = (const float*)d_in[1];
    const float* slope = (const float*)d_in[2];
    const float* ampli = (const float*)d_in[3];
    float* out = (float*)d_out;

    // harness poisons d_out with 0xAA; we accumulate atomically -> zero first
    hipMemsetAsync(out, 0, (size_t)out_size * sizeof(float), stream);

    psl_fused<<<NBLK, 256, 0, stream>>>(x, thres, slope, ampli, out);
}

// Round 18
// 97.057 us; speedup vs baseline: 2.6317x; 1.0619x over previous
//
#include <hip/hip_runtime.h>

// out[n][o] = sum_{s,i} tanh(slope[s][i][o]*x[n][i] - thres[s][i][o]) * ampli[s][i][o]^2
// N_DATA=128, N_SYN=8, IN_DIM=784, OUT_DIM=128
//
// R14: VGPR=152 full-unroll -> latency-bound at 3 waves/SIMD. Fixed (R17: VGPR=28).
// R17: fused+atomics = 43us, WRITE_SIZE 29.36MB == 7.34M atomics * 4B ->
//      memory-side RMW write-through; 171G atomics/s == the ceiling. Atomics,
//      not compute, pin the kernel. (R12's "atomics free" was wrong: two-phase
//      moved the same bytes as plain stores.)
// R18: cut partials 4x + zero RMW. Phase1 folds ALL s inside the block
//      (s-inner loop, constant-stride walk; x reused 8x per LDS read),
//      1024-thr blocks, 448 blocks (28 waves/CU), NACC=4, plain stores of
//      1.84M partials (7.34MB, L2-resident). Phase2 = R13 float4 gather,
//      fan-in 112 (16 groups x 7 loads), 512 thr. No atomics, no memset.

#define N_DATA  128
#define N_SYN   8
#define IN_DIM  784
#define OUT_DIM 128

#define NTILE   32                    // n per block (phase 1)
#define NSUBS   8                     // 1024 thr / 128 o
#define NACC    4                     // n per thread = NTILE/NSUBS
#define ICHUNK  7                     // i per block
#define NICHUNK 112                   // 784 / 7
#define NTILES  4                     // 128 / 32
#define NBLK1   (NTILES * NICHUNK)    // 448 blocks, all s folded in
#define FANIN   NICHUNK               // 112 partial tiles per (ntile)
#define SSTEP   (IN_DIM * OUT_DIM)            // +100352: (s,il) -> (s+1,il)
#define ILSTEP  (OUT_DIM - N_SYN * SSTEP)     // (s=7,il) -> (s=0,il+1)

__global__ __launch_bounds__(1024, 2)
void psl_phase1(const float* __restrict__ x,      // [128][784]
                const float* __restrict__ thres,  // [8][784][128]
                const float* __restrict__ slope,  // [8][784][128]
                const float* __restrict__ ampli,  // [8][784][128]
                float* __restrict__ ws)           // [448][32][128] partials
{
    const int t    = threadIdx.x;
    const int o    = t & 127;        // lane->o, coalesced param loads
    const int nsub = t >> 7;         // 0..7, wave-uniform

    const int ic    = blockIdx.x % NICHUNK;
    const int ntile = blockIdx.x / NICHUNK;   // 0..3
    const int i0    = ic * ICHUNK;

    // x tile staged in LDS: [i][n], 7*32*4 = 896 B
    __shared__ float xs[ICHUNK][NTILE];
    if (t < ICHUNK * NTILE) {
        const int nl = t & (NTILE - 1);
        const int il = t >> 5;
        xs[il][nl] = x[(ntile * NTILE + nl) * IN_DIM + i0 + il];
    }
    __syncthreads();

    float acc[NACC];
#pragma unroll
    for (int k = 0; k < NACC; ++k) acc[k] = 0.f;
    float suma2 = 0.f;

    const float C = 2.8853900817779268f;  // 2*log2(e)
    // start at (s=0, il=0): ((0*784 + i0)*128) + o
    int idx = i0 * OUT_DIM + o;

#pragma unroll 1
    for (int il = 0; il < ICHUNK; ++il) {
        // x for this il, reused across all 8 s (broadcast float4 -> conflict-free)
        const float4 xv = *reinterpret_cast<const float4*>(&xs[il][nsub * NACC]);

#pragma unroll 2
        for (int s = 0; s < N_SYN; ++s) {
            const float sl = slope[idx];
            const float th = thres[idx];
            const float am = ampli[idx];

            const float a2   = am * am;
            suma2 += a2;                      // n-independent, hoisted
            const float m2a2 = -2.f * a2;
            const float slC  = sl * C;
            const float thC  = th * C;

            {
                float z = __builtin_fmaf(slC, xv.x, -thC);
                float r = __builtin_amdgcn_rcpf(__builtin_amdgcn_exp2f(z) + 1.f);
                acc[0] = __builtin_fmaf(m2a2, r, acc[0]);
            }
            {
                float z = __builtin_fmaf(slC, xv.y, -thC);
                float r = __builtin_amdgcn_rcpf(__builtin_amdgcn_exp2f(z) + 1.f);
                acc[1] = __builtin_fmaf(m2a2, r, acc[1]);
            }
            {
                float z = __builtin_fmaf(slC, xv.z, -thC);
                float r = __builtin_amdgcn_rcpf(__builtin_amdgcn_exp2f(z) + 1.f);
                acc[2] = __builtin_fmaf(m2a2, r, acc[2]);
            }
            {
                float z = __builtin_fmaf(slC, xv.w, -thC);
                float r = __builtin_amdgcn_rcpf(__builtin_amdgcn_exp2f(z) + 1.f);
                acc[3] = __builtin_fmaf(m2a2, r, acc[3]);
            }

            idx += SSTEP;                     // (s,il) -> (s+1,il)
        }
        idx += ILSTEP;                        // (8,il) -> (0,il+1)
    }

    // store partials: ws[blockIdx][nsub*4+k][o], coalesced across o
    float* wsb = ws + (size_t)blockIdx.x * (NTILE * OUT_DIM);
#pragma unroll
    for (int k = 0; k < NACC; ++k) {
        wsb[(nsub * NACC + k) * OUT_DIM + o] = acc[k] + suma2;
    }
}

// one block per n, 512 thr: 16 j-groups x 32 float4-cols; each sums 7 tiles.
__global__ __launch_bounds__(512)
void psl_phase2(const float* __restrict__ ws,   // [448][32][128]
                float* __restrict__ out)        // [128][128]
{
    const int t  = threadIdx.x;      // 0..511
    const int g  = t >> 5;           // 0..15 : j-group
    const int o4 = t & 31;           // float4 column
    const int n  = blockIdx.x;       // 0..127
    const int ntile = n >> 5;
    const int nl    = n & 31;

    __shared__ float red[16][OUT_DIM];   // 8 KB

    // tile c row base: ((ntile*112 + c)*32 + nl)*128 floats
    const float4* base = reinterpret_cast<const float4*>(
        ws + (((size_t)(ntile * FANIN + g) * NTILE + nl) * OUT_DIM)) + o4;
    const size_t jstep = (size_t)16 * NTILE * OUT_DIM / 4;   // 16 tiles ahead

    float4 acc = make_float4(0.f, 0.f, 0.f, 0.f);
#pragma unroll
    for (int m = 0; m < FANIN / 16; ++m) {               // 7 iterations
        const float4 v = base[(size_t)m * jstep];
        acc.x += v.x; acc.y += v.y; acc.z += v.z; acc.w += v.w;
    }
    *reinterpret_cast<float4*>(&red[g][o4 * 4]) = acc;
    __syncthreads();

    if (t < OUT_DIM) {
        float s = 0.f;
#pragma unroll
        for (int g2 = 0; g2 < 16; ++g2) s += red[g2][t];
        out[n * OUT_DIM + t] = s;
    }
}

extern "C" void kernel_launch(void* const* d_in, const int* in_sizes, int n_in,
                              void* d_out, int out_size, void* d_ws, size_t ws_size,
                              hipStream_t stream) {
    const float* x     = (const float*)d_in[0];
    const float* thres = (const float*)d_in[1];
    const float* slope = (const float*)d_in[2];
    const float* ampli = (const float*)d_in[3];
    float* out = (float*)d_out;
    float* ws  = (float*)d_ws;   // uses 448*32*128*4 = 7.34 MB

    psl_phase1<<<NBLK1, 1024, 0, stream>>>(x, thres, slope, ampli, ws);
    psl_phase2<<<N_DATA, 512, 0, stream>>>(ws, out);
}